// Round 1
// baseline (163.618 us; speedup 1.0000x reference)
//
#include <hip/hip_runtime.h>

// ---------------- problem constants ----------------
#define T_LEN   1048576
#define NPAD    1049600            // T_LEN + 2*512
#define NFRAMES 2049
#define BATCH   8
#define NJ      (BATCH * NFRAMES)  // 16392 total frames
#define CUT     513
#define MROWS   1026               // 2*CUT, interleaved (real,imag) pairs
#define MPAD    1152               // 9 tiles of 128
#define OUT_BF  (CUT * NFRAMES)    // per-batch output stride

typedef __attribute__((ext_vector_type(8))) short bf16x8_t;
typedef __attribute__((ext_vector_type(4))) float f32x4_t;

// bf16 round-to-nearest-even from f32 (manual, avoids API surprises)
static __device__ __forceinline__ ushort f2bf(float f) {
    union { float f; unsigned u; } a;
    a.f = f;
    unsigned r = a.u + 0x7fffu + ((a.u >> 16) & 1u);
    return (ushort)(r >> 16);
}

// async global -> LDS, 16 bytes per lane; lds dest must be wave-uniform base
static __device__ __forceinline__ void gl_lds16(const ushort* g, ushort* s) {
    __builtin_amdgcn_global_load_lds(
        (__attribute__((address_space(1))) void*)g,
        (__attribute__((address_space(3))) void*)s,
        16, 0, 0);
}

// ---------------- prep 1: reflect-pad + bf16 convert ----------------
// xpad[b][i], i in [0, NPAD): reflect padding of input row b.
__global__ void pad_kernel(const float* __restrict__ in, ushort* __restrict__ xpad) {
    int g  = blockIdx.x * 256 + threadIdx.x;   // chunk of 4 elements
    int b  = g / (NPAD / 4);
    int c  = g - b * (NPAD / 4);
    int i0 = c * 4;
    const float* inb = in + (size_t)b * T_LEN;
    ushort4 o;
    if (i0 >= 512 && i0 + 3 < 512 + T_LEN) {
        const float4 v = *(const float4*)(inb + (i0 - 512));
        o = make_ushort4(f2bf(v.x), f2bf(v.y), f2bf(v.z), f2bf(v.w));
    } else {
        ushort tmp[4];
        for (int t = 0; t < 4; ++t) {
            int i = i0 + t;
            int src = (i < 512) ? (512 - i)
                    : (i < 512 + T_LEN) ? (i - 512)
                    : (2 * T_LEN + 510 - i);
            tmp[t] = f2bf(inb[src]);
        }
        o = make_ushort4(tmp[0], tmp[1], tmp[2], tmp[3]);
    }
    *(ushort4*)(xpad + (size_t)b * NPAD + i0) = o;
}

// ---------------- prep 2: rearrange + bf16-convert basis ----------------
// A2[2f+h][k] = basis[f + h*CUT][k]; rows [MROWS, MPAD) zeroed.
__global__ void basis_kernel(const float* __restrict__ fb, ushort* __restrict__ A2) {
    int g  = blockIdx.x * 256 + threadIdx.x;  // MPAD*256 threads, 4 cols each
    int r  = g >> 8;
    int cq = (g & 255) * 4;
    ushort4 o;
    if (r < MROWS) {
        int f = r >> 1, h = r & 1;
        const float4 v = *(const float4*)(fb + (size_t)(f + h * CUT) * 1024 + cq);
        o = make_ushort4(f2bf(v.x), f2bf(v.y), f2bf(v.z), f2bf(v.w));
    } else {
        o = make_ushort4(0, 0, 0, 0);
    }
    *(ushort4*)(A2 + (size_t)r * 1024 + cq) = o;
}

// ---------------- GEMM + magnitude epilogue ----------------
// C[m][j] = sum_k A2[m][k] * frames[j][k], frames[j][k] = xpad[b][n*512+k]
// out[b][f][n] = sqrt(C[2f][j]^2 + C[2f+1][j]^2 + eps)
__global__ __launch_bounds__(256) void gemm_kernel(
        const ushort* __restrict__ A2, const ushort* __restrict__ xpad,
        float* __restrict__ out, const float* __restrict__ epsp) {
    __shared__ __align__(16) ushort ldsA[128 * 64];
    __shared__ __align__(16) ushort ldsB[128 * 64];

    const int tid  = threadIdx.x;
    const int wave = tid >> 6, lane = tid & 63;
    const int quad = lane >> 4, l15 = lane & 15;
    const int m0 = blockIdx.x * 128;
    const int j0 = blockIdx.y * 128;
    const int wm = (wave >> 1) * 64;   // wave's m offset in tile
    const int wj = (wave & 1) * 64;    // wave's j offset in tile

    f32x4_t acc[4][4] = {};

    // staging address precompute: 4 issues/wave for A and for B.
    // issue q covers tile rows [(wave*4+q)*8, +8); lane L -> row +L/8, col chunk L%8.
    const int sr = lane >> 3;          // 0..7
    const int sc = (lane & 7) * 8;     // col element (8 bf16 = 16 B)
    int aoff[4], boff[4];
    for (int q = 0; q < 4; ++q) {
        int r = (wave * 4 + q) * 8 + sr;
        aoff[q] = (m0 + r) * 1024 + sc;          // A2 row-major, ld=1024; MPAD covers bounds
        int j = j0 + r; if (j > NJ - 1) j = NJ - 1;   // clamp padded frames
        int b = j / NFRAMES;
        int n = j - b * NFRAMES;
        boff[q] = b * NPAD + n * 512 + sc;       // frames ld = HOP = 512
    }

    for (int kt = 0; kt < 16; ++kt) {
        const int k0 = kt * 64;
        __syncthreads();   // protect previous iter's LDS reads
        for (int q = 0; q < 4; ++q) {
            gl_lds16(A2 + aoff[q] + k0, &ldsA[(wave * 4 + q) * 512]);
            gl_lds16(xpad + boff[q] + k0, &ldsB[(wave * 4 + q) * 512]);
        }
        __syncthreads();   // staging visible to all
        for (int kk = 0; kk < 2; ++kk) {
            bf16x8_t af[4], bf[4];
            const int co = kk * 32 + quad * 8;
            for (int i = 0; i < 4; ++i)
                af[i] = *(const bf16x8_t*)&ldsA[(wm + i * 16 + l15) * 64 + co];
            for (int jx = 0; jx < 4; ++jx)
                bf[jx] = *(const bf16x8_t*)&ldsB[(wj + jx * 16 + l15) * 64 + co];
            for (int i = 0; i < 4; ++i)
                for (int jx = 0; jx < 4; ++jx)
                    acc[i][jx] = __builtin_amdgcn_mfma_f32_16x16x32_bf16(
                        af[i], bf[jx], acc[i][jx], 0, 0, 0);
        }
    }

    // epilogue: C/D layout col=lane&15, row=quad*4+reg.
    // rows (4q,4q+1) -> f0 = M/2; rows (4q+2,4q+3) -> f0+1. All lane-local.
    const float eps = *epsp;
    for (int tj = 0; tj < 4; ++tj) {
        const int j = j0 + wj + tj * 16 + l15;
        if (j >= NJ) continue;
        const int b = j / NFRAMES;
        const int n = j - b * NFRAMES;
        float* ob = out + (size_t)b * OUT_BF + n;
        for (int ti = 0; ti < 4; ++ti) {
            const int M  = m0 + wm + ti * 16 + quad * 4;
            const int f0 = M >> 1;
            f32x4_t a = acc[ti][tj];
            if (f0 < CUT)
                ob[(size_t)f0 * NFRAMES] = sqrtf(a.x * a.x + a.y * a.y + eps);
            if (f0 + 1 < CUT)
                ob[(size_t)(f0 + 1) * NFRAMES] = sqrtf(a.z * a.z + a.w * a.w + eps);
        }
    }
}

extern "C" void kernel_launch(void* const* d_in, const int* in_sizes, int n_in,
                              void* d_out, int out_size, void* d_ws, size_t ws_size,
                              hipStream_t stream) {
    const float* in   = (const float*)d_in[0];
    const float* fb   = (const float*)d_in[1];
    const float* epsp = (const float*)d_in[2];
    float* out = (float*)d_out;

    ushort* A2   = (ushort*)d_ws;                                  // MPAD*1024 bf16 = 2.36 MB
    ushort* xpad = (ushort*)((char*)d_ws + (size_t)MPAD * 1024 * 2); // 8*NPAD bf16 = 16.8 MB

    pad_kernel<<<dim3(BATCH * (NPAD / 4) / 256), dim3(256), 0, stream>>>(in, xpad);
    basis_kernel<<<dim3(MPAD), dim3(256), 0, stream>>>(fb, A2);
    // grid: x = m-tiles (fastest -> adjacent blocks share B tile in L2), y = j-tiles
    gemm_kernel<<<dim3(MPAD / 128, (NJ + 127) / 128), dim3(256), 0, stream>>>(A2, xpad, out, epsp);
}

// Round 2
// 134.758 us; speedup vs baseline: 1.2142x; 1.2142x over previous
//
#include <hip/hip_runtime.h>

// ---------------- problem constants ----------------
#define T_LEN   1048576
#define NPAD    1049600            // T_LEN + 2*512
#define NFRAMES 2049
#define BATCH   8
#define NJ      (BATCH * NFRAMES)  // 16392 total frames
#define NSEG    2050               // seg rows per batch (s*512 windows incl. final)
#define CUT     513
#define MROWS   1026               // 2*CUT, interleaved (real,imag) pairs
#define MPAD    1152               // 9 tiles of 128
#define OUT_BF  (CUT * NFRAMES)    // per-batch output stride

typedef __attribute__((ext_vector_type(8))) short bf16x8_t;
typedef __attribute__((ext_vector_type(4))) float f32x4_t;

static __device__ __forceinline__ ushort f2bf(float f) {
    union { float f; unsigned u; } a;
    a.f = f;
    unsigned r = a.u + 0x7fffu + ((a.u >> 16) & 1u);
    return (ushort)(r >> 16);
}

// async global -> LDS, 16 bytes/lane; LDS dest = wave-uniform base + lane*16
static __device__ __forceinline__ void gl_lds16(const ushort* g, ushort* s) {
    __builtin_amdgcn_global_load_lds(
        (__attribute__((address_space(1))) void*)g,
        (__attribute__((address_space(3))) void*)s,
        16, 0, 0);
}

// ---------------- prep 1: reflect-pad + bf16 convert ----------------
__global__ void pad_kernel(const float* __restrict__ in, ushort* __restrict__ xpad) {
    int g  = blockIdx.x * 256 + threadIdx.x;   // chunk of 8 elements
    int b  = g / (NPAD / 8);
    int c  = g - b * (NPAD / 8);
    int i0 = c * 8;
    const float* inb = in + (size_t)b * T_LEN;
    ushort o[8];
    if (i0 >= 512 && i0 + 7 < 512 + T_LEN) {
        const float4 v0 = *(const float4*)(inb + (i0 - 512));
        const float4 v1 = *(const float4*)(inb + (i0 - 512) + 4);
        o[0]=f2bf(v0.x); o[1]=f2bf(v0.y); o[2]=f2bf(v0.z); o[3]=f2bf(v0.w);
        o[4]=f2bf(v1.x); o[5]=f2bf(v1.y); o[6]=f2bf(v1.z); o[7]=f2bf(v1.w);
    } else {
        for (int t = 0; t < 8; ++t) {
            int i = i0 + t;
            int src = (i < 512) ? (512 - i)
                    : (i < 512 + T_LEN) ? (i - 512)
                    : (2 * T_LEN + 510 - i);
            o[t] = f2bf(inb[src]);
        }
    }
    *(ulonglong2*)(xpad + (size_t)b * NPAD + i0) = *(ulonglong2*)o;
}

// ---------------- prep 2: rearrange + bf16-convert basis ----------------
// A2[2f+h][k] = basis[f + h*CUT][k]; rows [MROWS, MPAD) zeroed.
__global__ void basis_kernel(const float* __restrict__ fb, ushort* __restrict__ A2) {
    int g  = blockIdx.x * 256 + threadIdx.x;
    int r  = g >> 8;
    int cq = (g & 255) * 4;
    ushort4 o;
    if (r < MROWS) {
        int f = r >> 1, h = r & 1;
        const float4 v = *(const float4*)(fb + (size_t)(f + h * CUT) * 1024 + cq);
        o = make_ushort4(f2bf(v.x), f2bf(v.y), f2bf(v.z), f2bf(v.w));
    } else {
        o = make_ushort4(0, 0, 0, 0);
    }
    *(ushort4*)(A2 + (size_t)r * 1024 + cq) = o;
}

// ---------------- GEMM (hop-split) + magnitude epilogue ----------------
// C[m][j] = sum_{k'=0..511} A0[m][k']*seg(Sj)[k'] + A1[m][k']*seg(Sj+1)[k']
//   where A0 = A2 cols [0,512), A1 = A2 cols [512,1024),
//   seg(S)[k'] = xpad[S/NSEG][(S%NSEG)*512 + k'],  Sj = j + b(j).
// LDS layout XOR-swizzled: LDS chunk c (16B) of row r holds global chunk c^(r&7),
// implemented by permuting per-lane *global* source addresses in global_load_lds.
__global__ __launch_bounds__(256) void gemm_kernel(
        const ushort* __restrict__ A2, const ushort* __restrict__ xpad,
        float* __restrict__ out, const float* __restrict__ epsp) {
    __shared__ __align__(16) ushort ldsA0[128 * 64];
    __shared__ __align__(16) ushort ldsA1[128 * 64];
    __shared__ __align__(16) ushort ldsB [136 * 64];

    const int tid  = threadIdx.x;
    const int wave = tid >> 6, lane = tid & 63;
    const int quad = lane >> 4, l15 = lane & 15;
    const int m0 = blockIdx.x * 128;
    const int j0 = blockIdx.y * 128;
    const int wm = (wave >> 1) * 64;
    const int wj = (wave & 1) * 64;

    const int sr  = lane >> 3;                 // staged row within 8-row group
    const int sc8 = ((lane & 7) ^ sr) * 8;     // XOR-swizzled source chunk (elems)

    const int b0 = j0 / NFRAMES;
    const int S0 = j0 + b0;                    // global seg index of LDS B row 0

    // staging addresses (element offsets; add k0 per iter)
    int aoff[4], boff[4], boffx = 0;
    for (int t = 0; t < 4; ++t) {
        const int r = (wave * 4 + t) * 8 + sr;
        aoff[t] = (m0 + r) * 1024 + sc8;
        int S = S0 + r; if (S > BATCH * NSEG - 1) S = BATCH * NSEG - 1;
        int bb = S / NSEG, ss = S - bb * NSEG;
        boff[t] = bb * NPAD + ss * 512 + sc8;
    }
    {   // extra B issue (rows 128..135), wave 0 only
        int S = S0 + 128 + sr; if (S > BATCH * NSEG - 1) S = BATCH * NSEG - 1;
        int bb = S / NSEG, ss = S - bb * NSEG;
        boffx = bb * NPAD + ss * 512 + sc8;
    }

    // per-lane B fragment base rows (handles batch-boundary shift)
    int rowb[4];
    for (int jx = 0; jx < 4; ++jx) {
        const int j = j0 + wj + jx * 16 + l15;
        rowb[jx] = wj + jx * 16 + l15 + (j / NFRAMES - b0);
    }

    f32x4_t acc[4][4] = {};

    for (int kt = 0; kt < 8; ++kt) {
        const int k0 = kt * 64;
        __syncthreads();
        for (int t = 0; t < 4; ++t) {
            gl_lds16(A2 + aoff[t] + k0,        &ldsA0[(wave * 4 + t) * 512]);
            gl_lds16(A2 + aoff[t] + 512 + k0,  &ldsA1[(wave * 4 + t) * 512]);
            gl_lds16(xpad + boff[t] + k0,      &ldsB [(wave * 4 + t) * 512]);
        }
        if (wave == 0) gl_lds16(xpad + boffx + k0, &ldsB[16 * 512]);
        __syncthreads();
        for (int kk = 0; kk < 2; ++kk) {
            const int cb = kk * 4 + quad;      // within-window chunk 0..7
            bf16x8_t a0[4], a1[4], bf0[4], bf1[4];
            const int asw = (cb ^ (l15 & 7)) * 8;
            for (int i = 0; i < 4; ++i) {
                const int ro = (wm + i * 16 + l15) * 64;
                a0[i] = *(const bf16x8_t*)&ldsA0[ro + asw];
                a1[i] = *(const bf16x8_t*)&ldsA1[ro + asw];
            }
            for (int jx = 0; jx < 4; ++jx) {
                const int r0 = rowb[jx];
                const int r1 = r0 + 1;
                bf0[jx] = *(const bf16x8_t*)&ldsB[r0 * 64 + ((cb ^ (r0 & 7)) * 8)];
                bf1[jx] = *(const bf16x8_t*)&ldsB[r1 * 64 + ((cb ^ (r1 & 7)) * 8)];
            }
            for (int i = 0; i < 4; ++i)
                for (int jx = 0; jx < 4; ++jx) {
                    acc[i][jx] = __builtin_amdgcn_mfma_f32_16x16x32_bf16(
                        a0[i], bf0[jx], acc[i][jx], 0, 0, 0);
                    acc[i][jx] = __builtin_amdgcn_mfma_f32_16x16x32_bf16(
                        a1[i], bf1[jx], acc[i][jx], 0, 0, 0);
                }
        }
    }

    // epilogue: C/D layout col=lane&15 (-> j), row=quad*4+reg (-> M)
    const float eps = *epsp;
    for (int tj = 0; tj < 4; ++tj) {
        const int j = j0 + wj + tj * 16 + l15;
        if (j >= NJ) continue;
        const int b = j / NFRAMES;
        const int n = j - b * NFRAMES;
        float* ob = out + (size_t)b * OUT_BF + n;
        for (int ti = 0; ti < 4; ++ti) {
            const int M  = m0 + wm + ti * 16 + quad * 4;
            const int f0 = M >> 1;
            f32x4_t a = acc[ti][tj];
            if (f0 < CUT)
                ob[(size_t)f0 * NFRAMES] = sqrtf(a.x * a.x + a.y * a.y + eps);
            if (f0 + 1 < CUT)
                ob[(size_t)(f0 + 1) * NFRAMES] = sqrtf(a.z * a.z + a.w * a.w + eps);
        }
    }
}

extern "C" void kernel_launch(void* const* d_in, const int* in_sizes, int n_in,
                              void* d_out, int out_size, void* d_ws, size_t ws_size,
                              hipStream_t stream) {
    const float* in   = (const float*)d_in[0];
    const float* fb   = (const float*)d_in[1];
    const float* epsp = (const float*)d_in[2];
    float* out = (float*)d_out;

    ushort* A2   = (ushort*)d_ws;                                    // MPAD*1024*2B = 2.36 MB
    ushort* xpad = (ushort*)((char*)d_ws + (size_t)MPAD * 1024 * 2); // 8*NPAD*2B = 16.8 MB

    pad_kernel<<<dim3(BATCH * (NPAD / 8) / 256), dim3(256), 0, stream>>>(in, xpad);
    basis_kernel<<<dim3(MPAD), dim3(256), 0, stream>>>(fb, A2);
    gemm_kernel<<<dim3(MPAD / 128, (NJ + 127) / 128), dim3(256), 0, stream>>>(A2, xpad, out, epsp);
}